// Round 5
// baseline (118.557 us; speedup 1.0000x reference)
//
#include <hip/hip_runtime.h>

// MHA: B=4, T=1024, D=1024, H=16, HD=64. Causal mask, interleaved RoPE.
// bf16 MFMA (16x16x32) everywhere, fp32 accumulate.
// R5: GEMMs -> 4-deep counted-vmcnt pipeline (stage t+3 at iter t, one
// s_barrier/iter, vmcnt(2*L) steady wait, never 0 until tail). LDS packs
// 2 m-rows per 128B row, chunk ^= (row&7) swizzle via pre-swizzled global
// source => 2-way-max bank aliasing (free). qkv 128x384 grid 256 (1/CU),
// oproj 128x128 grid 256.

#define T_SEQ 1024
#define NH    16
#define HDIM  64
#define DM    1024
#define MTOK  4096   // B*T

typedef __attribute__((ext_vector_type(8))) short short8;
typedef __attribute__((ext_vector_type(4))) float f32x4;
typedef unsigned short u16;

__device__ __forceinline__ u16 f2bf(float f) {
  unsigned int u = __builtin_bit_cast(unsigned int, f);
  u += 0x7fffu + ((u >> 16) & 1u);
  return (u16)(u >> 16);
}

// async global->LDS, 16B per lane. LDS dest must be wave-uniform base + lane*16.
__device__ __forceinline__ void gll16(const void* g, void* l) {
  __builtin_amdgcn_global_load_lds(
      (const __attribute__((address_space(1))) unsigned int*)(unsigned long long)(g),
      (__attribute__((address_space(3))) unsigned int*)(unsigned int)(unsigned long long)(l),
      16, 0, 0);
}

template<int N> __device__ __forceinline__ void waitvm() {
  if constexpr (N == 8)      asm volatile("s_waitcnt vmcnt(8)" ::: "memory");
  else if constexpr (N == 4) asm volatile("s_waitcnt vmcnt(4)" ::: "memory");
  else if constexpr (N == 2) asm volatile("s_waitcnt vmcnt(2)" ::: "memory");
  else                       asm volatile("s_waitcnt vmcnt(0)" ::: "memory");
}

// ---------------- prep: x->bf16, W->bf16 (fused qkv+o), rope tables ----------------
__global__ void prep_kernel(const float* __restrict__ x,
                            const float* __restrict__ Wq, const float* __restrict__ Wk,
                            const float* __restrict__ Wv, const float* __restrict__ Wo,
                            u16* __restrict__ xb, u16* __restrict__ wall,
                            float* __restrict__ ctab, float* __restrict__ stab) {
  const int bid = blockIdx.x, tid = threadIdx.x;
  if (bid < 8192) {
    const float* src;
    u16* dst;
    int i;
    if (bid < 4096) {
      src = x; dst = xb; i = bid * 256 + tid;
    } else {
      const int w = (bid - 4096) >> 10;
      src = w == 0 ? Wq : w == 1 ? Wk : w == 2 ? Wv : Wo;
      dst = wall + (size_t)w * (DM * DM);
      i = ((bid - 4096) & 1023) * 256 + tid;
    }
    float4 f = ((const float4*)src)[i];
    unsigned long long pk = (unsigned long long)f2bf(f.x)
                          | ((unsigned long long)f2bf(f.y) << 16)
                          | ((unsigned long long)f2bf(f.z) << 32)
                          | ((unsigned long long)f2bf(f.w) << 48);
    ((unsigned long long*)dst)[i] = pk;
  } else {
    const int idx = (bid - 8192) * 256 + tid;  // T*32
    const int t = idx >> 5, i = idx & 31;
    float inv = powf(10000.f, -(float)i * (1.0f / 32.0f));
    float f = (float)t * inv;
    ctab[idx] = cosf(f);
    stab[idx] = sinf(f);
  }
}

// ---------------- 4-deep counted-vmcnt pipelined GEMM mainloop ----------------
// A:[M][1024] bf16, Bw:[N][1024] bf16 (row = output col). BK=32, NT=32.
// 512 threads = 8 waves (2M x 4N). Per-wave output (BM/2) x (BN/4).
// LDS: [4 buf][rows/2][8 chunks x 16B]; LDS-row r holds K0..31 of m=2r
// (chunks 0-3) and m=2r+1 (chunks 4-7); physical chunk = logical ^ (r&7)
// (inverse swizzle applied on GLOBAL source; reads use same XOR).
// Pipeline: stage t+3 at iter t; top-of-iter waits: own vmcnt(2L) (stage t
// landed, 2 tiles in flight) + lgkmcnt(0) (WAR drain), then s_barrier.
template<int BM, int BN, int AL, int BL, int MI, int NJ>
__device__ __forceinline__ void gemm_pipe4(
    const u16* __restrict__ A, const u16* __restrict__ Bw,
    int m0, int n0, u16* As, u16* Bs, f32x4 acc[MI][NJ]) {
  const int tid = threadIdx.x, lane = tid & 63, wave = tid >> 6;
  const int wr = wave >> 2, wc = wave & 3;
  const int NT = DM / 32;

  auto STG = [&](int t, int b) {
#pragma unroll
    for (int l = 0; l < AL; ++l) {
      const int idx = l * 512 + tid, r = idx >> 3, c = (idx & 7) ^ (r & 7);
      gll16(&A[(size_t)(m0 + 2 * r + (c >> 2)) * DM + t * 32 + (c & 3) * 8],
            &As[b * (BM * 32) + idx * 8]);
    }
#pragma unroll
    for (int l = 0; l < BL; ++l) {
      const int idx = l * 512 + tid, r = idx >> 3, c = (idx & 7) ^ (r & 7);
      gll16(&Bw[(size_t)(n0 + 2 * r + (c >> 2)) * DM + t * 32 + (c & 3) * 8],
            &Bs[b * (BN * 32) + idx * 8]);
    }
  };

  STG(0, 0); STG(1, 1); STG(2, 2);

  // t-invariant LDS fragment offsets (u16 units)
  const int mrow = lane & 15, q = lane >> 4;
  int aoff[MI], boff[NJ];
#pragma unroll
  for (int i = 0; i < MI; ++i) {
    const int m = wr * (MI * 16) + i * 16 + mrow, r = m >> 1;
    const int p = (((m & 1) << 2) + q) ^ (r & 7);
    aoff[i] = r * 64 + p * 8;
  }
#pragma unroll
  for (int j = 0; j < NJ; ++j) {
    const int n = wc * (NJ * 16) + j * 16 + mrow, r = n >> 1;
    const int p = (((n & 1) << 2) + q) ^ (r & 7);
    boff[j] = r * 64 + p * 8;
  }

  for (int t = 0; t < NT; ++t) {
    if (t < NT - 2)       waitvm<2 * (AL + BL)>();
    else if (t == NT - 2) waitvm<AL + BL>();
    else                  waitvm<0>();
    asm volatile("s_waitcnt lgkmcnt(0)" ::: "memory");
    __builtin_amdgcn_s_barrier();
    if (t + 3 < NT) STG(t + 3, (t + 3) & 3);
    const int boa = (t & 3) * (BM * 32), bob = (t & 3) * (BN * 32);
    short8 af[MI], bf[NJ];
#pragma unroll
    for (int i = 0; i < MI; ++i) af[i] = *(const short8*)&As[boa + aoff[i]];
#pragma unroll
    for (int j = 0; j < NJ; ++j) bf[j] = *(const short8*)&Bs[bob + boff[j]];
#pragma unroll
    for (int i = 0; i < MI; ++i)
#pragma unroll
      for (int j = 0; j < NJ; ++j)
        acc[i][j] = __builtin_amdgcn_mfma_f32_16x16x32_bf16(af[i], bf[j], acc[i][j], 0, 0, 0);
  }
}

// ---------------- fused QKV projection + bias + RoPE + layout ----------------
// Tile 128x384, grid (3072/384=8) x (4096/128=32) = 256 blocks = 1/CU.
__global__ __launch_bounds__(512, 2) void qkv_kernel(
    const u16* __restrict__ xb, const u16* __restrict__ wqkv,
    const float* __restrict__ bq, const float* __restrict__ bk, const float* __restrict__ bv,
    const float* __restrict__ ctab, const float* __restrict__ stab,
    u16* __restrict__ qbuf, u16* __restrict__ kbuf, u16* __restrict__ vt) {
  __shared__ __align__(16) u16 As[4 * 128 * 32];   // 32 KB
  __shared__ __align__(16) u16 Bs[4 * 384 * 32];   // 96 KB
  const int m0 = blockIdx.y * 128;
  const int n0 = blockIdx.x * 384;      // fused col across Wq|Wk|Wv
  f32x4 acc[4][6];
#pragma unroll
  for (int i = 0; i < 4; ++i)
#pragma unroll
    for (int j = 0; j < 6; ++j)
#pragma unroll
      for (int r = 0; r < 4; ++r) acc[i][j][r] = 0.f;
  gemm_pipe4<128, 384, 1, 3, 4, 6>(xb, wqkv, m0, n0, As, Bs, acc);

  const int lane = threadIdx.x & 63, wave = threadIdx.x >> 6;
  const int wr = wave >> 2, wc = wave & 3;
#pragma unroll
  for (int i = 0; i < 4; ++i) {
#pragma unroll
    for (int j = 0; j < 6; ++j) {
      const int e = n0 + wc * 96 + j * 16 + (lane & 15);   // global fused col
      const int mode = e >> 10;                             // 0=q 1=k 2=v (uniform per j-block)
      const float* bias = mode == 0 ? bq : (mode == 1 ? bk : bv);
      const float bval = bias[e & 1023];
      const int h = (e >> 6) & 15, hd = e & 63;
#pragma unroll
      for (int r = 0; r < 4; ++r) {
        const int m = m0 + wr * 64 + i * 16 + ((lane >> 4) * 4) + r;
        const int b = m >> 10, t = m & 1023;
        float v = acc[i][j][r] + bval;
        if (mode < 2) {
          float p = __shfl_xor(v, 1);  // partner within the (even,odd) pair
          const int fi = hd >> 1;
          const float cc = ctab[t * 32 + fi], ss = stab[t * 32 + fi];
          v = (hd & 1) ? (v * cc + p * ss) : (v * cc - p * ss);
          u16* dst = mode == 0 ? qbuf : kbuf;
          dst[(((size_t)(b * NH + h) * T_SEQ + t) << 6) + hd] = f2bf(v);
        } else {
          vt[(((size_t)(b * NH + h) * HDIM + hd) << 10) + t] = f2bf(v);
        }
      }
    }
  }
}

// ---------------- flash attention (unchanged from R4) ----------------
__global__ __launch_bounds__(256) void attn_kernel(
    const u16* __restrict__ qbuf, const u16* __restrict__ kbuf,
    const u16* __restrict__ vtb, u16* __restrict__ ctx) {
  __shared__ __align__(16) u16 Ks[2][64 * 64];   // [kv][hd] swizzled
  __shared__ __align__(16) u16 Vs[2][64 * 64];   // [hd][kv] swizzled (V^T tile)
  __shared__ __align__(16) u16 Psm[4][16 * 64];  // per-wave P, swizzled
  const int bh = blockIdx.x;
  const int b = bh >> 4, h = bh & 15;
  const int tid = threadIdx.x, lane = tid & 63, wave = tid >> 6;
  const u16* Qp = qbuf + (size_t)bh * T_SEQ * HDIM;
  const u16* Kp = kbuf + (size_t)bh * T_SEQ * HDIM;
  const u16* Vp = vtb + (size_t)bh * HDIM * T_SEQ;
  u16* Pw = &Psm[wave][0];

  const int srow = tid >> 3;                     // staging row (0..31, +32 for c=1)
  const int schx = ((tid & 7) ^ (srow & 7)) * 8; // pre-swizzled chunk (u16 offset)
  const int lx = lane & 7;                       // row&7 for all read rows below

#define STG(kvt, bb)                                                            \
  do {                                                                          \
    _Pragma("unroll") for (int c = 0; c < 2; ++c) {                             \
      const int rr = c * 32 + srow;                                             \
      gll16(&Kp[(kvt) * 4096 + rr * 64 + schx], &Ks[bb][c * 2048 + tid * 8]);   \
      gll16(&Vp[(size_t)rr * T_SEQ + (kvt) * 64 + schx], &Vs[bb][c * 2048 + tid * 8]); \
    }                                                                           \
  } while (0)

  for (int phase = 0; phase < 2; ++phase) {
    const int qt = phase ? (15 - (int)blockIdx.y) : (int)blockIdx.y;
    const int q0 = qt * 64;
    const int nkv = qt + 1;
    const int qrow = q0 + wave * 16 + (lane & 15);
    const short8 qf0 = *(const short8*)&Qp[qrow * 64 + ((lane >> 4) * 8)];
    const short8 qf1 = *(const short8*)&Qp[qrow * 64 + 32 + ((lane >> 4) * 8)];

    f32x4 acc_o[4];
    float m_r[4], l_r[4];
#pragma unroll
    for (int i = 0; i < 4; ++i) {
#pragma unroll
      for (int r = 0; r < 4; ++r) acc_o[i][r] = 0.f;
      m_r[i] = -__builtin_inff();
      l_r[i] = 0.f;
    }

    __syncthreads();   // previous phase's readers done before restaging buf0
    STG(0, 0);
    int cur = 0;

    for (int kvt = 0; kvt < nkv; ++kvt) {
      __syncthreads();                       // buf[cur] staged (vmcnt drained)
      if (kvt + 1 < nkv) STG(kvt + 1, cur ^ 1);

      // S = Q K^T (16x64 per wave)
      f32x4 sacc[4];
#pragma unroll
      for (int cb = 0; cb < 4; ++cb) {
#pragma unroll
        for (int r = 0; r < 4; ++r) sacc[cb][r] = 0.f;
        const int krow = cb * 16 + (lane & 15);
        const short8 kf0 = *(const short8*)&Ks[cur][krow * 64 + (((lane >> 4) ^ lx) * 8)];
        const short8 kf1 = *(const short8*)&Ks[cur][krow * 64 + (((4 + (lane >> 4)) ^ lx) * 8)];
        sacc[cb] = __builtin_amdgcn_mfma_f32_16x16x32_bf16(qf0, kf0, sacc[cb], 0, 0, 0);
        sacc[cb] = __builtin_amdgcn_mfma_f32_16x16x32_bf16(qf1, kf1, sacc[cb], 0, 0, 0);
      }
      // scale + causal mask
      const int trow_base = q0 + wave * 16 + ((lane >> 4) * 4);
#pragma unroll
      for (int cb = 0; cb < 4; ++cb) {
        const int scol = kvt * 64 + cb * 16 + (lane & 15);
#pragma unroll
        for (int r = 0; r < 4; ++r) {
          float sv = sacc[cb][r] * 0.125f;
          sacc[cb][r] = (scol > trow_base + r) ? -__builtin_inff() : sv;
        }
      }
      // online softmax (rows live across 16 lanes x 4 col-blocks)
      float mt[4];
#pragma unroll
      for (int r = 0; r < 4; ++r)
        mt[r] = fmaxf(fmaxf(sacc[0][r], sacc[1][r]), fmaxf(sacc[2][r], sacc[3][r]));
#pragma unroll
      for (int off = 1; off < 16; off <<= 1)
#pragma unroll
        for (int r = 0; r < 4; ++r) mt[r] = fmaxf(mt[r], __shfl_xor(mt[r], off));
      float sf[4], lt[4];
#pragma unroll
      for (int r = 0; r < 4; ++r) {
        const float mn = fmaxf(m_r[r], mt[r]);
        sf[r] = __expf(m_r[r] - mn);
        m_r[r] = mn;
        lt[r] = 0.f;
      }
#pragma unroll
      for (int cb = 0; cb < 4; ++cb)
#pragma unroll
        for (int r = 0; r < 4; ++r) {
          const float p = __expf(sacc[cb][r] - m_r[r]);
          sacc[cb][r] = p;
          lt[r] += p;
        }
#pragma unroll
      for (int off = 1; off < 16; off <<= 1)
#pragma unroll
        for (int r = 0; r < 4; ++r) lt[r] += __shfl_xor(lt[r], off);
#pragma unroll
      for (int r = 0; r < 4; ++r) l_r[r] = l_r[r] * sf[r] + lt[r];
#pragma unroll
      for (int hb = 0; hb < 4; ++hb)
#pragma unroll
        for (int r = 0; r < 4; ++r) acc_o[hb][r] *= sf[r];

      // P (C-layout) -> LDS (swizzled) -> A-layout
#pragma unroll
      for (int cb = 0; cb < 4; ++cb)
#pragma unroll
        for (int r = 0; r < 4; ++r) {
          const int prow = (lane >> 4) * 4 + r;
          Pw[prow * 64 + ((cb * 16 + (lane & 15)) ^ ((prow & 7) << 3))] = f2bf(sacc[cb][r]);
        }

      // O += P V
      const int prr = lane & 15;
#pragma unroll
      for (int kc = 0; kc < 2; ++kc) {
        const short8 pf = *(const short8*)&Pw[prr * 64 + (((kc * 4 + (lane >> 4)) ^ lx) * 8)];
#pragma unroll
        for (int hb = 0; hb < 4; ++hb) {
          const int vrow = hb * 16 + (lane & 15);
          const short8 vf = *(const short8*)&Vs[cur][vrow * 64 + (((kc * 4 + (lane >> 4)) ^ lx) * 8)];
          acc_o[hb] = __builtin_amdgcn_mfma_f32_16x16x32_bf16(pf, vf, acc_o[hb], 0, 0, 0);
        }
      }
      cur ^= 1;
    }

    // epilogue: ctx[b][t][h][hd] bf16
#pragma unroll
    for (int hb = 0; hb < 4; ++hb) {
      const int hd = hb * 16 + (lane & 15);
#pragma unroll
      for (int r = 0; r < 4; ++r) {
        const int t = q0 + wave * 16 + ((lane >> 4) * 4) + r;
        const float v = acc_o[hb][r] / l_r[r];
        ctx[((size_t)(b * T_SEQ + t) * NH + h) * HDIM + hd] = f2bf(v);
      }
    }
  }
#undef STG
}

// ---------------- output projection -> fp32 d_out ----------------
// Tile 128x128, grid (1024/128=8) x (4096/128=32) = 256 blocks.
__global__ __launch_bounds__(512, 2) void oproj_kernel(
    const u16* __restrict__ ctx, const u16* __restrict__ Wob,
    const float* __restrict__ bo, float* __restrict__ out) {
  __shared__ __align__(16) u16 As[4 * 128 * 32];   // 32 KB
  __shared__ __align__(16) u16 Bs[4 * 128 * 32];   // 32 KB
  const int m0 = blockIdx.y * 128, n0 = blockIdx.x * 128;
  f32x4 acc[4][2];
#pragma unroll
  for (int i = 0; i < 4; ++i)
#pragma unroll
    for (int j = 0; j < 2; ++j)
#pragma unroll
      for (int r = 0; r < 4; ++r) acc[i][j][r] = 0.f;
  gemm_pipe4<128, 128, 1, 1, 4, 2>(ctx, Wob, m0, n0, As, Bs, acc);
  const int lane = threadIdx.x & 63, wave = threadIdx.x >> 6;
  const int wr = wave >> 2, wc = wave & 3;
#pragma unroll
  for (int i = 0; i < 4; ++i)
#pragma unroll
    for (int j = 0; j < 2; ++j) {
      const int e = n0 + wc * 32 + j * 16 + (lane & 15);
      const float bval = bo[e];
#pragma unroll
      for (int r = 0; r < 4; ++r) {
        const int m = m0 + wr * 64 + i * 16 + ((lane >> 4) * 4) + r;
        out[(size_t)m * DM + e] = acc[i][j][r] + bval;
      }
    }
}

extern "C" void kernel_launch(void* const* d_in, const int* in_sizes, int n_in,
                              void* d_out, int out_size, void* d_ws, size_t ws_size,
                              hipStream_t stream) {
  const float* x  = (const float*)d_in[0];
  const float* Wq = (const float*)d_in[1];
  const float* bq = (const float*)d_in[2];
  const float* Wk = (const float*)d_in[3];
  const float* bk = (const float*)d_in[4];
  const float* Wv = (const float*)d_in[5];
  const float* bv = (const float*)d_in[6];
  const float* Wo = (const float*)d_in[7];
  const float* bo = (const float*)d_in[8];

  char* w = (char*)d_ws;
  u16* xb   = (u16*)(w);
  u16* wall = (u16*)(w + (8ull << 20));   // Wq|Wk|Wv|Wo bf16, 2MB each
  u16* wob  = (u16*)(w + (14ull << 20));
  u16* qb   = (u16*)(w + (16ull << 20));
  u16* kb   = (u16*)(w + (24ull << 20));
  u16* vtb  = (u16*)(w + (32ull << 20));
  u16* ctxb = (u16*)(w + (40ull << 20));
  float* ctab = (float*)(w + (48ull << 20));
  float* stab = ctab + T_SEQ * 32;

  prep_kernel<<<dim3(8192 + 128), 256, 0, stream>>>(x, Wq, Wk, Wv, Wo, xb, wall, ctab, stab);
  qkv_kernel<<<dim3(3 * DM / 384, MTOK / 128), 512, 0, stream>>>(
      xb, wall, bq, bk, bv, ctab, stab, qb, kb, vtb);
  attn_kernel<<<dim3(64, 8), 256, 0, stream>>>(qb, kb, vtb, ctxb);
  oproj_kernel<<<dim3(DM / 128, MTOK / 128), 512, 0, stream>>>(ctxb, wob, bo, (float*)d_out);
}

// Round 6
// 115.439 us; speedup vs baseline: 1.0270x; 1.0270x over previous
//
#include <hip/hip_runtime.h>

// MHA: B=4, T=1024, D=1024, H=16, HD=64. Causal mask, interleaved RoPE.
// bf16 MFMA (16x16x32) everywhere, fp32 accumulate.
// R6: back to R4's proven schedule (stage-next, ds_read, MFMA, one
// full-drain __syncthreads) but sized for 3 resident blocks/CU:
// 128x128 tile, BK=32, dbuf LDS = 32KB, 256 thr. oproj 64x128 (24KB).
// Packed LDS rows (2 m-rows per 128B row) + chunk^=(row&7) swizzle via
// pre-swizzled global source (0 conflicts, verified R5). Bijective XCD
// swizzle on both GEMM grids.

#define T_SEQ 1024
#define NH    16
#define HDIM  64
#define DM    1024
#define MTOK  4096   // B*T

typedef __attribute__((ext_vector_type(8))) short short8;
typedef __attribute__((ext_vector_type(4))) float f32x4;
typedef unsigned short u16;

__device__ __forceinline__ u16 f2bf(float f) {
  unsigned int u = __builtin_bit_cast(unsigned int, f);
  u += 0x7fffu + ((u >> 16) & 1u);
  return (u16)(u >> 16);
}

// async global->LDS, 16B per lane. LDS dest must be wave-uniform base + lane*16.
__device__ __forceinline__ void gll16(const void* g, void* l) {
  __builtin_amdgcn_global_load_lds(
      (const __attribute__((address_space(1))) unsigned int*)(unsigned long long)(g),
      (__attribute__((address_space(3))) unsigned int*)(unsigned int)(unsigned long long)(l),
      16, 0, 0);
}

// ---------------- prep: x->bf16, W->bf16 (fused qkv+o), rope tables ----------------
__global__ void prep_kernel(const float* __restrict__ x,
                            const float* __restrict__ Wq, const float* __restrict__ Wk,
                            const float* __restrict__ Wv, const float* __restrict__ Wo,
                            u16* __restrict__ xb, u16* __restrict__ wall,
                            float* __restrict__ ctab, float* __restrict__ stab) {
  const int bid = blockIdx.x, tid = threadIdx.x;
  if (bid < 8192) {
    const float* src;
    u16* dst;
    int i;
    if (bid < 4096) {
      src = x; dst = xb; i = bid * 256 + tid;
    } else {
      const int w = (bid - 4096) >> 10;
      src = w == 0 ? Wq : w == 1 ? Wk : w == 2 ? Wv : Wo;
      dst = wall + (size_t)w * (DM * DM);
      i = ((bid - 4096) & 1023) * 256 + tid;
    }
    float4 f = ((const float4*)src)[i];
    unsigned long long pk = (unsigned long long)f2bf(f.x)
                          | ((unsigned long long)f2bf(f.y) << 16)
                          | ((unsigned long long)f2bf(f.z) << 32)
                          | ((unsigned long long)f2bf(f.w) << 48);
    ((unsigned long long*)dst)[i] = pk;
  } else {
    const int idx = (bid - 8192) * 256 + tid;  // T*32
    const int t = idx >> 5, i = idx & 31;
    float inv = powf(10000.f, -(float)i * (1.0f / 32.0f));
    float f = (float)t * inv;
    ctab[idx] = cosf(f);
    stab[idx] = sinf(f);
  }
}

// ---------------- double-buffered GEMM mainloop (R4 schedule, small tiles) ----------------
// A:[M][1024] bf16, Bw:[N][1024] bf16 (row = output col). BK=32, NT=32.
// 256 threads = 4 waves (2M x 2N). Per-wave output (BM/2) x (BN/2).
// LDS: [2 buf][rows/2][8 chunks x 16B]; LDS-row r holds K0..31 of m=2r
// (chunks 0-3) and m=2r+1 (chunks 4-7); physical chunk = logical ^ (r&7)
// (inverse swizzle on GLOBAL source; reads use same XOR). Verified 0-conflict.
// Schedule per iter: STAGE(t+1, buf^1); ds_read(buf); MFMA; __syncthreads.
template<int BM, int BN, int AL, int BL, int MI, int NJ>
__device__ __forceinline__ void gemm_dbuf(
    const u16* __restrict__ A, const u16* __restrict__ Bw,
    int m0, int n0, u16* As, u16* Bs, f32x4 acc[MI][NJ]) {
  const int tid = threadIdx.x, lane = tid & 63, wave = tid >> 6;
  const int wr = wave >> 1, wc = wave & 1;
  const int NT = DM / 32;

  // precomputed global element offsets per staging load (t-invariant part)
  size_t aofs[AL], bofs[BL];
  int adst[AL], bdst[BL];
#pragma unroll
  for (int l = 0; l < AL; ++l) {
    const int idx = l * 256 + tid, r = idx >> 3, c = (idx & 7) ^ (r & 7);
    aofs[l] = (size_t)(m0 + 2 * r + (c >> 2)) * DM + (c & 3) * 8;
    adst[l] = idx * 8;
  }
#pragma unroll
  for (int l = 0; l < BL; ++l) {
    const int idx = l * 256 + tid, r = idx >> 3, c = (idx & 7) ^ (r & 7);
    bofs[l] = (size_t)(n0 + 2 * r + (c >> 2)) * DM + (c & 3) * 8;
    bdst[l] = idx * 8;
  }

#define STGD(t, b)                                                        \
  do {                                                                    \
    _Pragma("unroll") for (int l = 0; l < AL; ++l)                        \
      gll16(&A[aofs[l] + (t) * 32], &As[(b) * (BM * 32) + adst[l]]);      \
    _Pragma("unroll") for (int l = 0; l < BL; ++l)                        \
      gll16(&Bw[bofs[l] + (t) * 32], &Bs[(b) * (BN * 32) + bdst[l]]);     \
  } while (0)

  // t-invariant LDS fragment offsets (u16 units)
  const int mrow = lane & 15, q = lane >> 4;
  int aoff[MI], boff[NJ];
#pragma unroll
  for (int i = 0; i < MI; ++i) {
    const int m = wr * (MI * 16) + i * 16 + mrow, r = m >> 1;
    const int p = (((m & 1) << 2) | q) ^ (r & 7);
    aoff[i] = r * 64 + p * 8;
  }
#pragma unroll
  for (int j = 0; j < NJ; ++j) {
    const int n = wc * (NJ * 16) + j * 16 + mrow, r = n >> 1;
    const int p = (((n & 1) << 2) | q) ^ (r & 7);
    boff[j] = r * 64 + p * 8;
  }

  STGD(0, 0);
  __syncthreads();
  for (int t = 0; t < NT; ++t) {
    if (t + 1 < NT) STGD(t + 1, (t + 1) & 1);
    const int boa = (t & 1) * (BM * 32), bob = (t & 1) * (BN * 32);
    short8 af[MI], bf[NJ];
#pragma unroll
    for (int i = 0; i < MI; ++i) af[i] = *(const short8*)&As[boa + aoff[i]];
#pragma unroll
    for (int j = 0; j < NJ; ++j) bf[j] = *(const short8*)&Bs[bob + boff[j]];
#pragma unroll
    for (int i = 0; i < MI; ++i)
#pragma unroll
      for (int j = 0; j < NJ; ++j)
        acc[i][j] = __builtin_amdgcn_mfma_f32_16x16x32_bf16(af[i], bf[j], acc[i][j], 0, 0, 0);
    __syncthreads();
  }
#undef STGD
}

// ---------------- fused QKV projection + bias + RoPE + layout ----------------
// Tile 128x128, grid 768 (1-D, XCD-swizzled) = 3 blocks/CU.
__global__ __launch_bounds__(256, 3) void qkv_kernel(
    const u16* __restrict__ xb, const u16* __restrict__ wqkv,
    const float* __restrict__ bq, const float* __restrict__ bk, const float* __restrict__ bv,
    const float* __restrict__ ctab, const float* __restrict__ stab,
    u16* __restrict__ qbuf, u16* __restrict__ kbuf, u16* __restrict__ vt) {
  __shared__ __align__(16) u16 As[2 * 128 * 32];   // 16 KB
  __shared__ __align__(16) u16 Bs[2 * 128 * 32];   // 16 KB
  const int lin = blockIdx.x;                      // 768 = 8 * 96
  const int swz = (lin & 7) * 96 + (lin >> 3);
  const int m0 = (swz / 24) * 128;
  const int n0 = (swz % 24) * 128;                 // fused col across Wq|Wk|Wv
  f32x4 acc[4][4];
#pragma unroll
  for (int i = 0; i < 4; ++i)
#pragma unroll
    for (int j = 0; j < 4; ++j)
#pragma unroll
      for (int r = 0; r < 4; ++r) acc[i][j][r] = 0.f;
  gemm_dbuf<128, 128, 2, 2, 4, 4>(xb, wqkv, m0, n0, As, Bs, acc);

  const int lane = threadIdx.x & 63, wave = threadIdx.x >> 6;
  const int wr = wave >> 1, wc = wave & 1;
  const int mode = n0 >> 10;                        // block fully within one mode
  const float* bias = mode == 0 ? bq : (mode == 1 ? bk : bv);
#pragma unroll
  for (int i = 0; i < 4; ++i) {
#pragma unroll
    for (int j = 0; j < 4; ++j) {
      const int e = n0 + wc * 64 + j * 16 + (lane & 15);   // global fused col
      const float bval = bias[e & 1023];
      const int h = (e >> 6) & 15, hd = e & 63;
#pragma unroll
      for (int r = 0; r < 4; ++r) {
        const int m = m0 + wr * 64 + i * 16 + ((lane >> 4) * 4) + r;
        const int b = m >> 10, t = m & 1023;
        float v = acc[i][j][r] + bval;
        if (mode < 2) {
          float p = __shfl_xor(v, 1);  // partner within the (even,odd) pair
          const int fi = hd >> 1;
          const float cc = ctab[t * 32 + fi], ss = stab[t * 32 + fi];
          v = (hd & 1) ? (v * cc + p * ss) : (v * cc - p * ss);
          u16* dst = mode == 0 ? qbuf : kbuf;
          dst[(((size_t)(b * NH + h) * T_SEQ + t) << 6) + hd] = f2bf(v);
        } else {
          vt[(((size_t)(b * NH + h) * HDIM + hd) << 10) + t] = f2bf(v);
        }
      }
    }
  }
}

// ---------------- flash attention (unchanged, passing) ----------------
__global__ __launch_bounds__(256) void attn_kernel(
    const u16* __restrict__ qbuf, const u16* __restrict__ kbuf,
    const u16* __restrict__ vtb, u16* __restrict__ ctx) {
  __shared__ __align__(16) u16 Ks[2][64 * 64];   // [kv][hd] swizzled
  __shared__ __align__(16) u16 Vs[2][64 * 64];   // [hd][kv] swizzled (V^T tile)
  __shared__ __align__(16) u16 Psm[4][16 * 64];  // per-wave P, swizzled
  const int bh = blockIdx.x;
  const int b = bh >> 4, h = bh & 15;
  const int tid = threadIdx.x, lane = tid & 63, wave = tid >> 6;
  const u16* Qp = qbuf + (size_t)bh * T_SEQ * HDIM;
  const u16* Kp = kbuf + (size_t)bh * T_SEQ * HDIM;
  const u16* Vp = vtb + (size_t)bh * HDIM * T_SEQ;
  u16* Pw = &Psm[wave][0];

  const int srow = tid >> 3;                     // staging row (0..31, +32 for c=1)
  const int schx = ((tid & 7) ^ (srow & 7)) * 8; // pre-swizzled chunk (u16 offset)
  const int lx = lane & 7;                       // row&7 for all read rows below

#define STG(kvt, bb)                                                            \
  do {                                                                          \
    _Pragma("unroll") for (int c = 0; c < 2; ++c) {                             \
      const int rr = c * 32 + srow;                                             \
      gll16(&Kp[(kvt) * 4096 + rr * 64 + schx], &Ks[bb][c * 2048 + tid * 8]);   \
      gll16(&Vp[(size_t)rr * T_SEQ + (kvt) * 64 + schx], &Vs[bb][c * 2048 + tid * 8]); \
    }                                                                           \
  } while (0)

  for (int phase = 0; phase < 2; ++phase) {
    const int qt = phase ? (15 - (int)blockIdx.y) : (int)blockIdx.y;
    const int q0 = qt * 64;
    const int nkv = qt + 1;
    const int qrow = q0 + wave * 16 + (lane & 15);
    const short8 qf0 = *(const short8*)&Qp[qrow * 64 + ((lane >> 4) * 8)];
    const short8 qf1 = *(const short8*)&Qp[qrow * 64 + 32 + ((lane >> 4) * 8)];

    f32x4 acc_o[4];
    float m_r[4], l_r[4];
#pragma unroll
    for (int i = 0; i < 4; ++i) {
#pragma unroll
      for (int r = 0; r < 4; ++r) acc_o[i][r] = 0.f;
      m_r[i] = -__builtin_inff();
      l_r[i] = 0.f;
    }

    __syncthreads();   // previous phase's readers done before restaging buf0
    STG(0, 0);
    int cur = 0;

    for (int kvt = 0; kvt < nkv; ++kvt) {
      __syncthreads();                       // buf[cur] staged (vmcnt drained)
      if (kvt + 1 < nkv) STG(kvt + 1, cur ^ 1);

      // S = Q K^T (16x64 per wave)
      f32x4 sacc[4];
#pragma unroll
      for (int cb = 0; cb < 4; ++cb) {
#pragma unroll
        for (int r = 0; r < 4; ++r) sacc[cb][r] = 0.f;
        const int krow = cb * 16 + (lane & 15);
        const short8 kf0 = *(const short8*)&Ks[cur][krow * 64 + (((lane >> 4) ^ lx) * 8)];
        const short8 kf1 = *(const short8*)&Ks[cur][krow * 64 + (((4 + (lane >> 4)) ^ lx) * 8)];
        sacc[cb] = __builtin_amdgcn_mfma_f32_16x16x32_bf16(qf0, kf0, sacc[cb], 0, 0, 0);
        sacc[cb] = __builtin_amdgcn_mfma_f32_16x16x32_bf16(qf1, kf1, sacc[cb], 0, 0, 0);
      }
      // scale + causal mask
      const int trow_base = q0 + wave * 16 + ((lane >> 4) * 4);
#pragma unroll
      for (int cb = 0; cb < 4; ++cb) {
        const int scol = kvt * 64 + cb * 16 + (lane & 15);
#pragma unroll
        for (int r = 0; r < 4; ++r) {
          float sv = sacc[cb][r] * 0.125f;
          sacc[cb][r] = (scol > trow_base + r) ? -__builtin_inff() : sv;
        }
      }
      // online softmax (rows live across 16 lanes x 4 col-blocks)
      float mt[4];
#pragma unroll
      for (int r = 0; r < 4; ++r)
        mt[r] = fmaxf(fmaxf(sacc[0][r], sacc[1][r]), fmaxf(sacc[2][r], sacc[3][r]));
#pragma unroll
      for (int off = 1; off < 16; off <<= 1)
#pragma unroll
        for (int r = 0; r < 4; ++r) mt[r] = fmaxf(mt[r], __shfl_xor(mt[r], off));
      float sf[4], lt[4];
#pragma unroll
      for (int r = 0; r < 4; ++r) {
        const float mn = fmaxf(m_r[r], mt[r]);
        sf[r] = __expf(m_r[r] - mn);
        m_r[r] = mn;
        lt[r] = 0.f;
      }
#pragma unroll
      for (int cb = 0; cb < 4; ++cb)
#pragma unroll
        for (int r = 0; r < 4; ++r) {
          const float p = __expf(sacc[cb][r] - m_r[r]);
          sacc[cb][r] = p;
          lt[r] += p;
        }
#pragma unroll
      for (int off = 1; off < 16; off <<= 1)
#pragma unroll
        for (int r = 0; r < 4; ++r) lt[r] += __shfl_xor(lt[r], off);
#pragma unroll
      for (int r = 0; r < 4; ++r) l_r[r] = l_r[r] * sf[r] + lt[r];
#pragma unroll
      for (int hb = 0; hb < 4; ++hb)
#pragma unroll
        for (int r = 0; r < 4; ++r) acc_o[hb][r] *= sf[r];

      // P (C-layout) -> LDS (swizzled) -> A-layout
#pragma unroll
      for (int cb = 0; cb < 4; ++cb)
#pragma unroll
        for (int r = 0; r < 4; ++r) {
          const int prow = (lane >> 4) * 4 + r;
          Pw[prow * 64 + ((cb * 16 + (lane & 15)) ^ ((prow & 7) << 3))] = f2bf(sacc[cb][r]);
        }

      // O += P V
      const int prr = lane & 15;
#pragma unroll
      for (int kc = 0; kc < 2; ++kc) {
        const short8 pf = *(const short8*)&Pw[prr * 64 + (((kc * 4 + (lane >> 4)) ^ lx) * 8)];
#pragma unroll
        for (int hb = 0; hb < 4; ++hb) {
          const int vrow = hb * 16 + (lane & 15);
          const short8 vf = *(const short8*)&Vs[cur][vrow * 64 + (((kc * 4 + (lane >> 4)) ^ lx) * 8)];
          acc_o[hb] = __builtin_amdgcn_mfma_f32_16x16x32_bf16(pf, vf, acc_o[hb], 0, 0, 0);
        }
      }
      cur ^= 1;
    }

    // epilogue: ctx[b][t][h][hd] bf16
#pragma unroll
    for (int hb = 0; hb < 4; ++hb) {
      const int hd = hb * 16 + (lane & 15);
#pragma unroll
      for (int r = 0; r < 4; ++r) {
        const int t = q0 + wave * 16 + ((lane >> 4) * 4) + r;
        const float v = acc_o[hb][r] / l_r[r];
        ctx[((size_t)(b * T_SEQ + t) * NH + h) * HDIM + hd] = f2bf(v);
      }
    }
  }
#undef STG
}

// ---------------- output projection -> fp32 d_out ----------------
// Tile 64x128, grid 512 (1-D, XCD-swizzled) = 2 blocks/CU.
__global__ __launch_bounds__(256, 2) void oproj_kernel(
    const u16* __restrict__ ctx, const u16* __restrict__ Wob,
    const float* __restrict__ bo, float* __restrict__ out) {
  __shared__ __align__(16) u16 As[2 * 64 * 32];    // 8 KB
  __shared__ __align__(16) u16 Bs[2 * 128 * 32];   // 16 KB
  const int lin = blockIdx.x;                      // 512 = 8 * 64
  const int swz = (lin & 7) * 64 + (lin >> 3);
  const int m0 = (swz / 8) * 64;
  const int n0 = (swz % 8) * 128;
  f32x4 acc[2][4];
#pragma unroll
  for (int i = 0; i < 2; ++i)
#pragma unroll
    for (int j = 0; j < 4; ++j)
#pragma unroll
      for (int r = 0; r < 4; ++r) acc[i][j][r] = 0.f;
  gemm_dbuf<64, 128, 1, 2, 2, 4>(ctx, Wob, m0, n0, As, Bs, acc);
  const int lane = threadIdx.x & 63, wave = threadIdx.x >> 6;
  const int wr = wave >> 1, wc = wave & 1;
#pragma unroll
  for (int i = 0; i < 2; ++i)
#pragma unroll
    for (int j = 0; j < 4; ++j) {
      const int e = n0 + wc * 64 + j * 16 + (lane & 15);
      const float bval = bo[e];
#pragma unroll
      for (int r = 0; r < 4; ++r) {
        const int m = m0 + wr * 32 + i * 16 + ((lane >> 4) * 4) + r;
        out[(size_t)m * DM + e] = acc[i][j][r] + bval;
      }
    }
}

extern "C" void kernel_launch(void* const* d_in, const int* in_sizes, int n_in,
                              void* d_out, int out_size, void* d_ws, size_t ws_size,
                              hipStream_t stream) {
  const float* x  = (const float*)d_in[0];
  const float* Wq = (const float*)d_in[1];
  const float* bq = (const float*)d_in[2];
  const float* Wk = (const float*)d_in[3];
  const float* bk = (const float*)d_in[4];
  const float* Wv = (const float*)d_in[5];
  const float* bv = (const float*)d_in[6];
  const float* Wo = (const float*)d_in[7];
  const float* bo = (const float*)d_in[8];

  char* w = (char*)d_ws;
  u16* xb   = (u16*)(w);
  u16* wall = (u16*)(w + (8ull << 20));   // Wq|Wk|Wv|Wo bf16, 2MB each
  u16* wob  = (u16*)(w + (14ull << 20));
  u16* qb   = (u16*)(w + (16ull << 20));
  u16* kb   = (u16*)(w + (24ull << 20));
  u16* vtb  = (u16*)(w + (32ull << 20));
  u16* ctxb = (u16*)(w + (40ull << 20));
  float* ctab = (float*)(w + (48ull << 20));
  float* stab = ctab + T_SEQ * 32;

  prep_kernel<<<dim3(8192 + 128), 256, 0, stream>>>(x, Wq, Wk, Wv, Wo, xb, wall, ctab, stab);
  qkv_kernel<<<dim3(768), 256, 0, stream>>>(
      xb, wall, bq, bk, bv, ctab, stab, qb, kb, vtb);
  attn_kernel<<<dim3(64, 8), 256, 0, stream>>>(qb, kb, vtb, ctxb);
  oproj_kernel<<<dim3(512), 256, 0, stream>>>(ctxb, wob, bo, (float*)d_out);
}